// Round 17
// baseline (165.307 us; speedup 1.0000x reference)
//
#include <hip/hip_runtime.h>
#include <hip/hip_bf16.h>
#include <math.h>

#define BB 64
#define LL 1024
#define EE 256
#define KK 8
#define EPB 8        // e-channels per xcorr group
#define CHUNKS (EE/EPB)

typedef __attribute__((ext_vector_type(8))) short  bfrag;   // 8 bf16 (4 VGPRs)
typedef __attribute__((ext_vector_type(4))) short  short4v; // 4 bf16 (8B)
typedef __attribute__((ext_vector_type(4))) float  f32x4;

// Maug tiled: per kb (8): 272 rows x 32 k shorts = 8704 shorts (17 x 512 chunks)
#define MT_KB 8704

// workspace layout (units: floats)
#define O_MHI    ((size_t)0)                    // 8*8704 shorts = 34816 floats
#define O_MLO    ((size_t)34816)                // 34816
#define O_BVAUG  ((size_t)69632)                // 16 floats
#define O_X      ((size_t)69696)                // 16777216: ThiT+TloT (gemm), then St (fft)
#define O_KPT    (O_X + (size_t)16777216)       // B*E*L ([b][e][l])
#define O_VSUB   (O_KPT + (size_t)16777216)     // B*L*16 = 1048576
#define O_MV     (O_VSUB + (size_t)1048576)     // B*L = 65536
#define O_STATS  (O_MV + (size_t)65536)
// xcorr partials (513 float2 per (b,chunk)) overlay the head of each group's own
// St slab (slab = EPB*LL = 8192 floats >= 1026) — consumed by that group first.

__device__ __forceinline__ float2 cmulf(float2 a, float2 b) {
    return make_float2(a.x * b.x - a.y * b.y, a.x * b.y + a.y * b.x);
}

__device__ __forceinline__ int PHY(int i) { return i + (i >> 4); }  // LDS pad

__device__ __forceinline__ void splitbf(float x, unsigned short& h, unsigned short& l) {
    __hip_bfloat16 hb = __float2bfloat16(x);
    float hf = __bfloat162float(hb);
    __hip_bfloat16 lb = __float2bfloat16(x - hf);
    h = *(unsigned short*)&hb;
    l = *(unsigned short*)&lb;
}

__device__ __forceinline__ void gload16(const unsigned short* g, unsigned short* l) {
    __builtin_amdgcn_global_load_lds(
        (const __attribute__((address_space(1))) unsigned int*)g,
        (__attribute__((address_space(3))) unsigned int*)l, 16, 0, 0);
}

__device__ __forceinline__ int slot_of(int r, int kq) { return (kq + (r >> 1)) & 3; }

// ---------------- kernel 1: Maug = [Wq^T Wk ; Wv rows 0..7,248..255], bf16 hi/lo, tiled+swizzled
__global__ __launch_bounds__(256) void build_maug(
    const float* __restrict__ Wq, const float* __restrict__ Wk,
    const float* __restrict__ Wv, const float* __restrict__ bv,
    unsigned short* __restrict__ mhiT, unsigned short* __restrict__ mloT,
    float* __restrict__ bvaug) {
    int n = blockIdx.x;   // 0..271
    int j = threadIdx.x;  // k: 0..255
    float acc;
    if (n < EE) {
        acc = 0.f;
        for (int e = 0; e < EE; ++e)
            acc += Wq[e * EE + n] * Wk[e * EE + j];
    } else {
        int t = n - EE;
        int c = (t < 8) ? t : (240 + t);
        acc = Wv[c * EE + j];
    }
    unsigned short h, l;
    splitbf(acc, h, l);
    const int kb = j >> 5, kq = (j >> 3) & 3;
    const size_t dst = (size_t)kb * MT_KB + n * 32 + slot_of(n, kq) * 8 + (j & 7);
    mhiT[dst] = h;
    mloT[dst] = l;
    if (n == 0 && j < 16) bvaug[j] = bv[(j < 8) ? j : (240 + j)];
}

// ---------------- kernel 1c: split T -> bf16 hi/lo in tiled+swizzled layout
__global__ __launch_bounds__(256) void split_T(
    const float* __restrict__ T,
    unsigned short* __restrict__ thiT, unsigned short* __restrict__ tloT) {
    const size_t g = (size_t)blockIdx.x * 256 + threadIdx.x;
    const size_t i = g * 8;
    const int s = (int)(i >> 8), k = (int)(i & 255);
    const int kb = k >> 5, kq = (k >> 3) & 3;
    const int st = s >> 6, row = s & 63;
    f32x4 v0 = *(const f32x4*)&T[i];
    f32x4 v1 = *(const f32x4*)&T[i + 4];
    short4v h0, l0, h1, l1;
#pragma unroll
    for (int j = 0; j < 4; ++j) {
        unsigned short h, l;
        splitbf(v0[j], h, l); h0[j] = (short)h; l0[j] = (short)l;
        splitbf(v1[j], h, l); h1[j] = (short)h; l1[j] = (short)l;
    }
    const size_t dst = ((size_t)(st * 8 + kb)) * 2048 + row * 32 + slot_of(row, kq) * 8;
    *(short4v*)&thiT[dst] = h0; *(short4v*)&thiT[dst + 4] = h1;
    *(short4v*)&tloT[dst] = l0; *(short4v*)&tloT[dst + 4] = l1;
}

// ---------------- kernel 1b: St[b][e][l] = S[b][l][e], 64x64 tile, float4 both sides
__global__ __launch_bounds__(256) void transpose_S(
    const float* __restrict__ S, float* __restrict__ St) {
    __shared__ float tile[64][65];
    const int b = blockIdx.z;
    const int l0 = blockIdx.x * 64, e0 = blockIdx.y * 64;
    const int tx = threadIdx.x & 15, ty = threadIdx.x >> 4;   // 16 x 16
#pragma unroll
    for (int r = 0; r < 4; ++r) {
        const int lr = ty + 16 * r;
        f32x4 v = *(const f32x4*)&S[((size_t)b * LL + l0 + lr) * EE + e0 + tx * 4];
#pragma unroll
        for (int i = 0; i < 4; ++i) tile[lr][tx * 4 + i] = v[i];
    }
    __syncthreads();
#pragma unroll
    for (int r = 0; r < 4; ++r) {
        const int er = ty + 16 * r;
        f32x4 v;
#pragma unroll
        for (int i = 0; i < 4; ++i) v[i] = tile[tx * 4 + i][er];
        *(f32x4*)&St[((size_t)b * EE + e0 + er) * LL + l0 + tx * 4] = v;
    }
}

// ---------------- kernel 2: MFMA GEMM, BM=64, 4 waves; A LDS-double-buffered (R16 best)
__global__ __launch_bounds__(256, 3) void gemm_mfma(
    const unsigned short* __restrict__ thiT, const unsigned short* __restrict__ tloT,
    const unsigned short* __restrict__ mhiT, const unsigned short* __restrict__ mloT,
    const float* __restrict__ bvaug,
    float* __restrict__ kp_t, float* __restrict__ vsub) {
    __shared__ alignas(16) unsigned short Ah[4096];   // 2 x (64 rows x 32)
    __shared__ alignas(16) unsigned short Al[4096];
    __shared__ alignas(16) unsigned short Bh[8704];   // 272 rows x 32
    __shared__ alignas(16) unsigned short Bl[8704];
    const int tid = threadIdx.x;
    const int w = tid >> 6, lane = tid & 63;
    const int lrow = lane & 15, lk = lane >> 4;
    const int st = blockIdx.x;
    const size_t s0 = (size_t)st * 64;
    const int bb = (int)(s0 >> 10), l0 = (int)(s0 & 1023);

    f32x4 acc[4][4];
    f32x4 acc2[4];
#pragma unroll
    for (int m = 0; m < 4; ++m) {
#pragma unroll
        for (int c = 0; c < 4; ++c) acc[m][c] = (f32x4){0.f, 0.f, 0.f, 0.f};
        acc2[m] = (f32x4){0.f, 0.f, 0.f, 0.f};
    }

    {
        const size_t tsel = (size_t)(st * 8 + 0) * 2048 + w * 512;
        gload16(thiT + tsel + lane * 8, &Ah[w * 512]);
        gload16(tloT + tsel + lane * 8, &Al[w * 512]);
    }

#pragma unroll
    for (int kb = 0; kb < 8; ++kb) {
        __syncthreads();
        const unsigned short* bsrcH = mhiT + (size_t)kb * MT_KB;
        const unsigned short* bsrcL = mloT + (size_t)kb * MT_KB;
#pragma unroll
        for (int q = 0; q < 4; ++q) {
            const int ch = q * 4 + w;
            gload16(bsrcH + ch * 512 + lane * 8, &Bh[ch * 512]);
            gload16(bsrcL + ch * 512 + lane * 8, &Bl[ch * 512]);
        }
        if (w == 0) {
            gload16(bsrcH + 16 * 512 + lane * 8, &Bh[16 * 512]);
            gload16(bsrcL + 16 * 512 + lane * 8, &Bl[16 * 512]);
        }
        __syncthreads();
        if (kb < 7) {
            const int ab = (kb + 1) & 1;
            const size_t tsel = (size_t)(st * 8 + kb + 1) * 2048 + w * 512;
            gload16(thiT + tsel + lane * 8, &Ah[ab * 2048 + w * 512]);
            gload16(tloT + tsel + lane * 8, &Al[ab * 2048 + w * 512]);
        }
        const int ao = (kb & 1) * 2048;
        bfrag ah[4], al[4];
#pragma unroll
        for (int m = 0; m < 4; ++m) {
            const int row = m * 16 + lrow;
            const int off = ao + row * 32 + slot_of(row, lk) * 8;
            ah[m] = *(const bfrag*)&Ah[off];
            al[m] = *(const bfrag*)&Al[off];
        }
#pragma unroll
        for (int c = 0; c < 4; ++c) {
            const int n = w * 64 + c * 16 + lrow;
            const int off = n * 32 + slot_of(n, lk) * 8;
            bfrag bh = *(const bfrag*)&Bh[off];
            bfrag bl = *(const bfrag*)&Bl[off];
#pragma unroll
            for (int m = 0; m < 4; ++m) {
                acc[m][c] = __builtin_amdgcn_mfma_f32_16x16x32_bf16(ah[m], bh, acc[m][c], 0, 0, 0);
                acc[m][c] = __builtin_amdgcn_mfma_f32_16x16x32_bf16(ah[m], bl, acc[m][c], 0, 0, 0);
                acc[m][c] = __builtin_amdgcn_mfma_f32_16x16x32_bf16(al[m], bh, acc[m][c], 0, 0, 0);
            }
        }
        if (w == 0) {
            const int n = EE + lrow;
            const int off = n * 32 + slot_of(n, lk) * 8;
            bfrag bh = *(const bfrag*)&Bh[off];
            bfrag bl = *(const bfrag*)&Bl[off];
#pragma unroll
            for (int m = 0; m < 4; ++m) {
                acc2[m] = __builtin_amdgcn_mfma_f32_16x16x32_bf16(ah[m], bh, acc2[m], 0, 0, 0);
                acc2[m] = __builtin_amdgcn_mfma_f32_16x16x32_bf16(ah[m], bl, acc2[m], 0, 0, 0);
                acc2[m] = __builtin_amdgcn_mfma_f32_16x16x32_bf16(al[m], bh, acc2[m], 0, 0, 0);
            }
        }
    }
#pragma unroll
    for (int m = 0; m < 4; ++m) {
        const int srow = m * 16 + lk * 4;
#pragma unroll
        for (int c = 0; c < 4; ++c) {
            const int n = w * 64 + c * 16 + lrow;
            *(f32x4*)&kp_t[((size_t)(bb * EE + n)) * LL + l0 + srow] = acc[m][c];
        }
    }
    if (w == 0) {
        const float bvv = bvaug[lrow];
#pragma unroll
        for (int m = 0; m < 4; ++m) {
            const int srow = m * 16 + lk * 4;
#pragma unroll
            for (int j = 0; j < 4; ++j)
                vsub[(s0 + srow + j) * 16 + lrow] = acc2[m][j] + bvv;
        }
    }
}

// ---------------- radix-4 Stockham stages 1..4 (stage 0 done in registers by caller).
// Input in `a`; 4 stages a->b->a->b->a: RESULT LANDS IN `a`. On-the-fly twiddles.
// NOTE: __syncthreads spans ALL groups in the block; groups run identical control flow.
template<bool INV>
__device__ __forceinline__ void fft1024_r4_tail(float2* a, float2* b, int tid) {
    float2* src = a;
    float2* dst = b;
#pragma unroll
    for (int t = 1; t < 5; ++t) {
        const int Ns = 1 << (2 * t);     // 4,16,64,256
        __syncthreads();
        const int j = tid;
        const int k = j & (Ns - 1);
        float sv, cv;
        __sincosf(-3.14159265358979323846f * (float)k / (float)(2 * Ns), &sv, &cv);
        float2 w1 = make_float2(cv, sv);
        float2 w2 = cmulf(w1, w1);
        float2 w3 = cmulf(w1, w2);
        if (INV) { w1.y = -w1.y; w2.y = -w2.y; w3.y = -w3.y; }
        float2 a0 = src[PHY(j)];
        float2 a1 = cmulf(w1, src[PHY(j + 256)]);
        float2 a2 = cmulf(w2, src[PHY(j + 512)]);
        float2 a3 = cmulf(w3, src[PHY(j + 768)]);
        float2 t0 = make_float2(a0.x + a2.x, a0.y + a2.y);
        float2 t1 = make_float2(a0.x - a2.x, a0.y - a2.y);
        float2 t2 = make_float2(a1.x + a3.x, a1.y + a3.y);
        float2 t3 = make_float2(a1.x - a3.x, a1.y - a3.y);
        float2 u3 = INV ? make_float2(-t3.y, t3.x) : make_float2(t3.y, -t3.x);
        const int base = ((j >> (2 * t)) << (2 * t + 2)) + k;
        dst[PHY(base)]          = make_float2(t0.x + t2.x, t0.y + t2.y);
        dst[PHY(base + Ns)]     = make_float2(t1.x + u3.x, t1.y + u3.y);
        dst[PHY(base + 2 * Ns)] = make_float2(t0.x - t2.x, t0.y - t2.y);
        dst[PHY(base + 3 * Ns)] = make_float2(t1.x - u3.x, t1.y - u3.y);
        float2* tmp = src; src = dst; dst = tmp;
    }
    __syncthreads();
}

// ---------------- full 5-stage radix-4 (used by ifft; result lands in `b`)
template<bool INV>
__device__ __forceinline__ void fft1024_r4(float2* a, float2* b, int tid) {
    float2* src = a;
    float2* dst = b;
#pragma unroll
    for (int t = 0; t < 5; ++t) {
        const int Ns = 1 << (2 * t);
        __syncthreads();
        const int j = tid;
        const int k = j & (Ns - 1);
        float sv, cv;
        __sincosf(-3.14159265358979323846f * (float)k / (float)(2 * Ns), &sv, &cv);
        float2 w1 = make_float2(cv, sv);
        float2 w2 = cmulf(w1, w1);
        float2 w3 = cmulf(w1, w2);
        if (INV) { w1.y = -w1.y; w2.y = -w2.y; w3.y = -w3.y; }
        float2 a0 = src[PHY(j)];
        float2 a1 = cmulf(w1, src[PHY(j + 256)]);
        float2 a2 = cmulf(w2, src[PHY(j + 512)]);
        float2 a3 = cmulf(w3, src[PHY(j + 768)]);
        float2 t0 = make_float2(a0.x + a2.x, a0.y + a2.y);
        float2 t1 = make_float2(a0.x - a2.x, a0.y - a2.y);
        float2 t2 = make_float2(a1.x + a3.x, a1.y + a3.y);
        float2 t3 = make_float2(a1.x - a3.x, a1.y - a3.y);
        float2 u3 = INV ? make_float2(-t3.y, t3.x) : make_float2(t3.y, -t3.x);
        const int base = ((j >> (2 * t)) << (2 * t + 2)) + k;
        dst[PHY(base)]          = make_float2(t0.x + t2.x, t0.y + t2.y);
        dst[PHY(base + Ns)]     = make_float2(t1.x + u3.x, t1.y + u3.y);
        dst[PHY(base + 2 * Ns)] = make_float2(t0.x - t2.x, t0.y - t2.y);
        dst[PHY(base + 3 * Ns)] = make_float2(t1.x - u3.x, t1.y - u3.y);
        float2* tmp = src; src = dst; dst = tmp;
    }
    __syncthreads();
}

// ---------------- kernel 3: 512 threads = 2 independent FFT groups per block.
// Group g (tid>>8) processes chunk 2*(blockIdx%16)+g with its own LDS buffers;
// block-wide barriers cover 2x work -> halved per-FFT barrier overhead.
__global__ __launch_bounds__(512) void xcorr_kernel(
    float* __restrict__ St, const float* __restrict__ kp_t) {
    __shared__ float2 bufA[2][1088];
    __shared__ float2 bufB[2][1088];
    const int tid = (int)threadIdx.x;
    const int grp = tid >> 8, t = tid & 255;
    const int b = blockIdx.x / (CHUNKS / 2);
    const int chunk = 2 * (blockIdx.x % (CHUNKS / 2)) + grp;
    float2* bA = bufA[grp];
    float2* bBv = bufB[grp];

    float2 p0 = make_float2(0.f, 0.f);
    float2 p1 = make_float2(0.f, 0.f);
    float px2 = 0.f;                      // f=512 (t==0 of each group)

    const size_t base = ((size_t)b * EE + (size_t)chunk * EPB) * LL;
    for (int ee = 0; ee < EPB; ++ee) {
        const size_t rbase = base + (size_t)ee * LL;
        __syncthreads();   // prior pacc reads of bA done (both groups)
        // ---- stage 0 in registers: loads ARE the stage-0 operands
        {
            float2 z0 = make_float2(St[rbase + t],        kp_t[rbase + t]);
            float2 z1 = make_float2(St[rbase + t + 256],  kp_t[rbase + t + 256]);
            float2 z2 = make_float2(St[rbase + t + 512],  kp_t[rbase + t + 512]);
            float2 z3 = make_float2(St[rbase + t + 768],  kp_t[rbase + t + 768]);
            float2 t0 = make_float2(z0.x + z2.x, z0.y + z2.y);
            float2 t1 = make_float2(z0.x - z2.x, z0.y - z2.y);
            float2 t2 = make_float2(z1.x + z3.x, z1.y + z3.y);
            float2 t3 = make_float2(z1.x - z3.x, z1.y - z3.y);
            float2 u3 = make_float2(t3.y, -t3.x);            // forward
            const int q = 4 * t;
            bA[PHY(q)]     = make_float2(t0.x + t2.x, t0.y + t2.y);
            bA[PHY(q + 1)] = make_float2(t1.x + u3.x, t1.y + u3.y);
            bA[PHY(q + 2)] = make_float2(t0.x - t2.x, t0.y - t2.y);
            bA[PHY(q + 3)] = make_float2(t1.x - u3.x, t1.y - u3.y);
        }
        fft1024_r4_tail<false>(bA, bBv, t);   // stages 1..4, result in bA
        {
            float2 A = bA[PHY(t)];
            float2 C = bA[PHY((1024 - t) & 1023)];
            p0.x += 0.5f * (A.x * C.y + A.y * C.x);
            p0.y += 0.25f * ((A.x * A.x + A.y * A.y) - (C.x * C.x + C.y * C.y));
        }
        {
            int f = t + 256;
            float2 A = bA[PHY(f)];
            float2 C = bA[PHY(1024 - f)];
            p1.x += 0.5f * (A.x * C.y + A.y * C.x);
            p1.y += 0.25f * ((A.x * A.x + A.y * A.y) - (C.x * C.x + C.y * C.y));
        }
        if (t == 0) {
            float2 A = bA[PHY(512)];
            px2 += A.x * A.y;
        }
    }
    float2* pp = (float2*)&St[base];      // own slab head (fully consumed above)
    pp[t] = p0;
    pp[t + 256] = p1;
    if (t == 0) pp[512] = make_float2(px2, 0.f);
}

// ---------------- kernel 4: per b: reduce partials, Hermitian irfft -> mean_value
__global__ __launch_bounds__(256) void ifft_kernel(
    const float* __restrict__ St, float* __restrict__ mv) {
    __shared__ float2 bufA[1088];
    __shared__ float2 bufB[1088];
    const int tid = threadIdx.x;
    const int b = blockIdx.x;
#pragma unroll
    for (int u = 0; u < 2; ++u) {
        int f = tid + (u << 8);            // 0..511
        float2 s = make_float2(0.f, 0.f);
        for (int c = 0; c < CHUNKS; ++c) {
            const float2* pp = (const float2*)&St[((size_t)b * EE + (size_t)c * EPB) * LL];
            float2 v = pp[f];
            s.x += v.x; s.y += v.y;
        }
        if (f == 0) s.y = 0.f;
        bufA[PHY(f)] = s;
        if (f > 0) bufA[PHY(1024 - f)] = make_float2(s.x, -s.y);
    }
    if (tid == 0) {
        float sx = 0.f;
        for (int c = 0; c < CHUNKS; ++c) {
            const float2* pp = (const float2*)&St[((size_t)b * EE + (size_t)c * EPB) * LL];
            sx += pp[512].x;
        }
        bufA[PHY(512)] = make_float2(sx, 0.f);
    }
    fft1024_r4<true>(bufA, bufB, tid);
    const float sc = 1.f / (1024.f * 256.f);
#pragma unroll
    for (int u = 0; u < 4; ++u) {
        int t = tid + (u << 8);
        mv[(size_t)b * LL + t] = bufB[PHY(t)].x * sc;
    }
}

// ---------------- kernel 5: batch-mean over b, argmax/argmin over tau
__global__ __launch_bounds__(1024) void argidx_kernel(
    const float* __restrict__ mv, int* __restrict__ istats) {
    __shared__ float smax[1024], smin[1024];
    __shared__ int imax[1024], imin[1024];
    const int t = threadIdx.x;
    float g = 0.f;
    for (int b = 0; b < BB; ++b) g += mv[(size_t)b * LL + t];
    smax[t] = g; smin[t] = g; imax[t] = t; imin[t] = t;
    __syncthreads();
    for (int s = 512; s > 0; s >>= 1) {
        if (t < s) {
            if (smax[t + s] > smax[t] ||
                (smax[t + s] == smax[t] && imax[t + s] < imax[t])) {
                smax[t] = smax[t + s]; imax[t] = imax[t + s];
            }
            if (smin[t + s] < smin[t] ||
                (smin[t + s] == smin[t] && imin[t + s] > imin[t])) {
                smin[t] = smin[t + s]; imin[t] = imin[t + s];
            }
        }
        __syncthreads();
    }
    if (t == 0) { istats[0] = imax[0]; istats[1] = imin[0]; }
}

// ---------------- kernel 6: per-b softmax weights at idx0 / idx1
__global__ __launch_bounds__(256) void softmax_kernel(
    const float* __restrict__ mv, const int* __restrict__ istats,
    float* __restrict__ w01) {
    __shared__ float red[256];
    const int b = blockIdx.x, t = threadIdx.x;
    const float scale = 0.0625f;
    const float* row = mv + (size_t)b * LL;
    float m = -INFINITY;
    for (int i = t; i < LL; i += 256) m = fmaxf(m, row[i]);
    red[t] = m; __syncthreads();
    for (int s = 128; s > 0; s >>= 1) {
        if (t < s) red[t] = fmaxf(red[t], red[t + s]);
        __syncthreads();
    }
    m = red[0]; __syncthreads();
    float sum = 0.f;
    for (int i = t; i < LL; i += 256) sum += expf((row[i] - m) * scale);
    red[t] = sum; __syncthreads();
    for (int s = 128; s > 0; s >>= 1) {
        if (t < s) red[t] += red[t + s];
        __syncthreads();
    }
    if (t == 0) {
        float denom = red[0];
        w01[b]      = expf((row[istats[0]] - m) * scale) / denom;
        w01[BB + b] = expf((row[istats[1]] - m) * scale) / denom;
    }
}

// ---------------- kernel 7: gather rolled vsub columns, scale, write out
__global__ __launch_bounds__(256) void out_kernel(
    const float* __restrict__ vsub, const int* __restrict__ istats,
    const float* __restrict__ w01, float* __restrict__ out) {
    const int i = blockIdx.x * 256 + threadIdx.x;
    const int half = (i >= BB * LL * KK) ? 1 : 0;
    const int j = i - half * BB * LL * KK;
    const int b = j / (LL * KK);
    const int rem = j % (LL * KK);
    const int l = rem / KK, kk = rem % KK;
    const int sh = istats[half];
    const int lr = (l + sh) & (LL - 1);
    const float w = w01[half * BB + b];
    out[i] = vsub[(size_t)(b * LL + lr) * 16 + half * 8 + kk] * w;
}

extern "C" void kernel_launch(void* const* d_in, const int* in_sizes, int n_in,
                              void* d_out, int out_size, void* d_ws, size_t ws_size,
                              hipStream_t stream) {
    const float* S  = (const float*)d_in[0];
    const float* T  = (const float*)d_in[1];
    const float* Wq = (const float*)d_in[2];
    const float* Wk = (const float*)d_in[4];
    const float* Wv = (const float*)d_in[6];
    const float* bv = (const float*)d_in[7];

    float* ws    = (float*)d_ws;
    unsigned short* mhiT = (unsigned short*)(ws + O_MHI);
    unsigned short* mloT = (unsigned short*)(ws + O_MLO);
    float* bvaug = ws + O_BVAUG;
    unsigned short* thiT = (unsigned short*)(ws + O_X);
    unsigned short* tloT = (unsigned short*)(ws + O_X + 8388608);
    float* st    = ws + O_X;                  // aliases ThiT/TloT (after gemm)
    float* kp_t  = ws + O_KPT;
    float* vsub  = ws + O_VSUB;
    float* mv    = ws + O_MV;
    float* stats = ws + O_STATS;
    int*   istats = (int*)stats;
    float* w01    = stats + 8;

    build_maug<<<272, 256, 0, stream>>>(Wq, Wk, Wv, bv, mhiT, mloT, bvaug);
    split_T<<<(BB * LL * EE) / (256 * 8), 256, 0, stream>>>(T, thiT, tloT);
    gemm_mfma<<<(BB * LL) / 64, 256, 0, stream>>>(thiT, tloT, mhiT, mloT, bvaug, kp_t, vsub);
    dim3 gT(LL / 64, EE / 64, BB);
    transpose_S<<<gT, 256, 0, stream>>>(S, st);   // overwrites ThiT/TloT (consumed by gemm)
    xcorr_kernel<<<BB * (CHUNKS / 2), 512, 0, stream>>>(st, kp_t);
    ifft_kernel<<<BB, 256, 0, stream>>>(st, mv);
    argidx_kernel<<<1, 1024, 0, stream>>>(mv, istats);
    softmax_kernel<<<BB, 256, 0, stream>>>(mv, istats, w01);
    out_kernel<<<(2 * BB * LL * KK) / 256, 256, 0, stream>>>(vsub, istats, w01, (float*)d_out);
}

// Round 18
// 160.066 us; speedup vs baseline: 1.0327x; 1.0327x over previous
//
#include <hip/hip_runtime.h>
#include <hip/hip_bf16.h>
#include <math.h>

#define BB 64
#define LL 1024
#define EE 256
#define KK 8
#define EPB 8        // e-channels per xcorr block
#define CHUNKS (EE/EPB)

typedef __attribute__((ext_vector_type(8))) short  bfrag;   // 8 bf16 (4 VGPRs)
typedef __attribute__((ext_vector_type(4))) short  short4v; // 4 bf16 (8B)
typedef __attribute__((ext_vector_type(4))) float  f32x4;

// Maug tiled: per kb (8): 272 rows x 32 k shorts = 8704 shorts (17 x 512 chunks)
#define MT_KB 8704

// workspace layout (units: floats)
#define O_MHI    ((size_t)0)                    // 8*8704 shorts = 34816 floats
#define O_MLO    ((size_t)34816)                // 34816
#define O_BVAUG  ((size_t)69632)                // 16 floats
#define O_X      ((size_t)69696)                // 16777216: ThiT+TloT (gemm), then St (fft)
#define O_KPT    (O_X + (size_t)16777216)       // B*E*L ([b][e][l])
#define O_VSUB   (O_KPT + (size_t)16777216)     // B*L*16 = 1048576
#define O_MV     (O_VSUB + (size_t)1048576)     // B*L = 65536
#define O_STATS  (O_MV + (size_t)65536)
// xcorr partials (513 float2 per (b,chunk)) overlay the head of each block's own
// St slab (slab = EPB*LL = 8192 floats >= 1026) — consumed by that block first.

__device__ __forceinline__ float2 cmulf(float2 a, float2 b) {
    return make_float2(a.x * b.x - a.y * b.y, a.x * b.y + a.y * b.x);
}

__device__ __forceinline__ int PHY(int i) { return i + (i >> 4); }  // LDS pad

__device__ __forceinline__ void splitbf(float x, unsigned short& h, unsigned short& l) {
    __hip_bfloat16 hb = __float2bfloat16(x);
    float hf = __bfloat162float(hb);
    __hip_bfloat16 lb = __float2bfloat16(x - hf);
    h = *(unsigned short*)&hb;
    l = *(unsigned short*)&lb;
}

__device__ __forceinline__ void gload16(const unsigned short* g, unsigned short* l) {
    __builtin_amdgcn_global_load_lds(
        (const __attribute__((address_space(1))) unsigned int*)g,
        (__attribute__((address_space(3))) unsigned int*)l, 16, 0, 0);
}

__device__ __forceinline__ int slot_of(int r, int kq) { return (kq + (r >> 1)) & 3; }

// ---------------- kernel 1: Maug = [Wq^T Wk ; Wv rows 0..7,248..255], bf16 hi/lo, tiled+swizzled
__global__ __launch_bounds__(256) void build_maug(
    const float* __restrict__ Wq, const float* __restrict__ Wk,
    const float* __restrict__ Wv, const float* __restrict__ bv,
    unsigned short* __restrict__ mhiT, unsigned short* __restrict__ mloT,
    float* __restrict__ bvaug) {
    int n = blockIdx.x;   // 0..271
    int j = threadIdx.x;  // k: 0..255
    float acc;
    if (n < EE) {
        acc = 0.f;
        for (int e = 0; e < EE; ++e)
            acc += Wq[e * EE + n] * Wk[e * EE + j];
    } else {
        int t = n - EE;
        int c = (t < 8) ? t : (240 + t);
        acc = Wv[c * EE + j];
    }
    unsigned short h, l;
    splitbf(acc, h, l);
    const int kb = j >> 5, kq = (j >> 3) & 3;
    const size_t dst = (size_t)kb * MT_KB + n * 32 + slot_of(n, kq) * 8 + (j & 7);
    mhiT[dst] = h;
    mloT[dst] = l;
    if (n == 0 && j < 16) bvaug[j] = bv[(j < 8) ? j : (240 + j)];
}

// ---------------- kernel 1c: split T -> bf16 hi/lo in tiled+swizzled layout
__global__ __launch_bounds__(256) void split_T(
    const float* __restrict__ T,
    unsigned short* __restrict__ thiT, unsigned short* __restrict__ tloT) {
    const size_t g = (size_t)blockIdx.x * 256 + threadIdx.x;
    const size_t i = g * 8;
    const int s = (int)(i >> 8), k = (int)(i & 255);
    const int kb = k >> 5, kq = (k >> 3) & 3;
    const int st = s >> 6, row = s & 63;
    f32x4 v0 = *(const f32x4*)&T[i];
    f32x4 v1 = *(const f32x4*)&T[i + 4];
    short4v h0, l0, h1, l1;
#pragma unroll
    for (int j = 0; j < 4; ++j) {
        unsigned short h, l;
        splitbf(v0[j], h, l); h0[j] = (short)h; l0[j] = (short)l;
        splitbf(v1[j], h, l); h1[j] = (short)h; l1[j] = (short)l;
    }
    const size_t dst = ((size_t)(st * 8 + kb)) * 2048 + row * 32 + slot_of(row, kq) * 8;
    *(short4v*)&thiT[dst] = h0; *(short4v*)&thiT[dst + 4] = h1;
    *(short4v*)&tloT[dst] = l0; *(short4v*)&tloT[dst + 4] = l1;
}

// ---------------- kernel 1b: St[b][e][l] = S[b][l][e], 64x64 tile, float4 both sides
__global__ __launch_bounds__(256) void transpose_S(
    const float* __restrict__ S, float* __restrict__ St) {
    __shared__ float tile[64][65];
    const int b = blockIdx.z;
    const int l0 = blockIdx.x * 64, e0 = blockIdx.y * 64;
    const int tx = threadIdx.x & 15, ty = threadIdx.x >> 4;   // 16 x 16
#pragma unroll
    for (int r = 0; r < 4; ++r) {
        const int lr = ty + 16 * r;
        f32x4 v = *(const f32x4*)&S[((size_t)b * LL + l0 + lr) * EE + e0 + tx * 4];
#pragma unroll
        for (int i = 0; i < 4; ++i) tile[lr][tx * 4 + i] = v[i];
    }
    __syncthreads();
#pragma unroll
    for (int r = 0; r < 4; ++r) {
        const int er = ty + 16 * r;
        f32x4 v;
#pragma unroll
        for (int i = 0; i < 4; ++i) v[i] = tile[tx * 4 + i][er];
        *(f32x4*)&St[((size_t)b * EE + e0 + er) * LL + l0 + tx * 4] = v;
    }
}

// ---------------- kernel 2: MFMA GEMM, BM=64, 4 waves; A LDS-double-buffered (R16 best)
__global__ __launch_bounds__(256, 3) void gemm_mfma(
    const unsigned short* __restrict__ thiT, const unsigned short* __restrict__ tloT,
    const unsigned short* __restrict__ mhiT, const unsigned short* __restrict__ mloT,
    const float* __restrict__ bvaug,
    float* __restrict__ kp_t, float* __restrict__ vsub) {
    __shared__ alignas(16) unsigned short Ah[4096];   // 2 x (64 rows x 32)
    __shared__ alignas(16) unsigned short Al[4096];
    __shared__ alignas(16) unsigned short Bh[8704];   // 272 rows x 32
    __shared__ alignas(16) unsigned short Bl[8704];
    const int tid = threadIdx.x;
    const int w = tid >> 6, lane = tid & 63;
    const int lrow = lane & 15, lk = lane >> 4;
    const int st = blockIdx.x;
    const size_t s0 = (size_t)st * 64;
    const int bb = (int)(s0 >> 10), l0 = (int)(s0 & 1023);

    f32x4 acc[4][4];
    f32x4 acc2[4];
#pragma unroll
    for (int m = 0; m < 4; ++m) {
#pragma unroll
        for (int c = 0; c < 4; ++c) acc[m][c] = (f32x4){0.f, 0.f, 0.f, 0.f};
        acc2[m] = (f32x4){0.f, 0.f, 0.f, 0.f};
    }

    {
        const size_t tsel = (size_t)(st * 8 + 0) * 2048 + w * 512;
        gload16(thiT + tsel + lane * 8, &Ah[w * 512]);
        gload16(tloT + tsel + lane * 8, &Al[w * 512]);
    }

#pragma unroll
    for (int kb = 0; kb < 8; ++kb) {
        __syncthreads();
        const unsigned short* bsrcH = mhiT + (size_t)kb * MT_KB;
        const unsigned short* bsrcL = mloT + (size_t)kb * MT_KB;
#pragma unroll
        for (int q = 0; q < 4; ++q) {
            const int ch = q * 4 + w;
            gload16(bsrcH + ch * 512 + lane * 8, &Bh[ch * 512]);
            gload16(bsrcL + ch * 512 + lane * 8, &Bl[ch * 512]);
        }
        if (w == 0) {
            gload16(bsrcH + 16 * 512 + lane * 8, &Bh[16 * 512]);
            gload16(bsrcL + 16 * 512 + lane * 8, &Bl[16 * 512]);
        }
        __syncthreads();
        if (kb < 7) {
            const int ab = (kb + 1) & 1;
            const size_t tsel = (size_t)(st * 8 + kb + 1) * 2048 + w * 512;
            gload16(thiT + tsel + lane * 8, &Ah[ab * 2048 + w * 512]);
            gload16(tloT + tsel + lane * 8, &Al[ab * 2048 + w * 512]);
        }
        const int ao = (kb & 1) * 2048;
        bfrag ah[4], al[4];
#pragma unroll
        for (int m = 0; m < 4; ++m) {
            const int row = m * 16 + lrow;
            const int off = ao + row * 32 + slot_of(row, lk) * 8;
            ah[m] = *(const bfrag*)&Ah[off];
            al[m] = *(const bfrag*)&Al[off];
        }
#pragma unroll
        for (int c = 0; c < 4; ++c) {
            const int n = w * 64 + c * 16 + lrow;
            const int off = n * 32 + slot_of(n, lk) * 8;
            bfrag bh = *(const bfrag*)&Bh[off];
            bfrag bl = *(const bfrag*)&Bl[off];
#pragma unroll
            for (int m = 0; m < 4; ++m) {
                acc[m][c] = __builtin_amdgcn_mfma_f32_16x16x32_bf16(ah[m], bh, acc[m][c], 0, 0, 0);
                acc[m][c] = __builtin_amdgcn_mfma_f32_16x16x32_bf16(ah[m], bl, acc[m][c], 0, 0, 0);
                acc[m][c] = __builtin_amdgcn_mfma_f32_16x16x32_bf16(al[m], bh, acc[m][c], 0, 0, 0);
            }
        }
        if (w == 0) {
            const int n = EE + lrow;
            const int off = n * 32 + slot_of(n, lk) * 8;
            bfrag bh = *(const bfrag*)&Bh[off];
            bfrag bl = *(const bfrag*)&Bl[off];
#pragma unroll
            for (int m = 0; m < 4; ++m) {
                acc2[m] = __builtin_amdgcn_mfma_f32_16x16x32_bf16(ah[m], bh, acc2[m], 0, 0, 0);
                acc2[m] = __builtin_amdgcn_mfma_f32_16x16x32_bf16(ah[m], bl, acc2[m], 0, 0, 0);
                acc2[m] = __builtin_amdgcn_mfma_f32_16x16x32_bf16(al[m], bh, acc2[m], 0, 0, 0);
            }
        }
    }
#pragma unroll
    for (int m = 0; m < 4; ++m) {
        const int srow = m * 16 + lk * 4;
#pragma unroll
        for (int c = 0; c < 4; ++c) {
            const int n = w * 64 + c * 16 + lrow;
            *(f32x4*)&kp_t[((size_t)(bb * EE + n)) * LL + l0 + srow] = acc[m][c];
        }
    }
    if (w == 0) {
        const float bvv = bvaug[lrow];
#pragma unroll
        for (int m = 0; m < 4; ++m) {
            const int srow = m * 16 + lk * 4;
#pragma unroll
            for (int j = 0; j < 4; ++j)
                vsub[(s0 + srow + j) * 16 + lrow] = acc2[m][j] + bvv;
        }
    }
}

// ---------------- radix-4 Stockham stages 1..4 (stage 0 done in registers by caller).
// Input in `a`; 4 stages a->b->a->b->a: RESULT LANDS IN `a`. On-the-fly twiddles.
template<bool INV>
__device__ __forceinline__ void fft1024_r4_tail(float2* a, float2* b, int tid) {
    float2* src = a;
    float2* dst = b;
#pragma unroll
    for (int t = 1; t < 5; ++t) {
        const int Ns = 1 << (2 * t);     // 4,16,64,256
        __syncthreads();
        const int j = tid;
        const int k = j & (Ns - 1);
        float sv, cv;
        __sincosf(-3.14159265358979323846f * (float)k / (float)(2 * Ns), &sv, &cv);
        float2 w1 = make_float2(cv, sv);
        float2 w2 = cmulf(w1, w1);
        float2 w3 = cmulf(w1, w2);
        if (INV) { w1.y = -w1.y; w2.y = -w2.y; w3.y = -w3.y; }
        float2 a0 = src[PHY(j)];
        float2 a1 = cmulf(w1, src[PHY(j + 256)]);
        float2 a2 = cmulf(w2, src[PHY(j + 512)]);
        float2 a3 = cmulf(w3, src[PHY(j + 768)]);
        float2 t0 = make_float2(a0.x + a2.x, a0.y + a2.y);
        float2 t1 = make_float2(a0.x - a2.x, a0.y - a2.y);
        float2 t2 = make_float2(a1.x + a3.x, a1.y + a3.y);
        float2 t3 = make_float2(a1.x - a3.x, a1.y - a3.y);
        float2 u3 = INV ? make_float2(-t3.y, t3.x) : make_float2(t3.y, -t3.x);
        const int base = ((j >> (2 * t)) << (2 * t + 2)) + k;
        dst[PHY(base)]          = make_float2(t0.x + t2.x, t0.y + t2.y);
        dst[PHY(base + Ns)]     = make_float2(t1.x + u3.x, t1.y + u3.y);
        dst[PHY(base + 2 * Ns)] = make_float2(t0.x - t2.x, t0.y - t2.y);
        dst[PHY(base + 3 * Ns)] = make_float2(t1.x - u3.x, t1.y - u3.y);
        float2* tmp = src; src = dst; dst = tmp;
    }
    __syncthreads();
}

// ---------------- full 5-stage radix-4 (used by ifft; result lands in `b`)
template<bool INV>
__device__ __forceinline__ void fft1024_r4(float2* a, float2* b, int tid) {
    float2* src = a;
    float2* dst = b;
#pragma unroll
    for (int t = 0; t < 5; ++t) {
        const int Ns = 1 << (2 * t);
        __syncthreads();
        const int j = tid;
        const int k = j & (Ns - 1);
        float sv, cv;
        __sincosf(-3.14159265358979323846f * (float)k / (float)(2 * Ns), &sv, &cv);
        float2 w1 = make_float2(cv, sv);
        float2 w2 = cmulf(w1, w1);
        float2 w3 = cmulf(w1, w2);
        if (INV) { w1.y = -w1.y; w2.y = -w2.y; w3.y = -w3.y; }
        float2 a0 = src[PHY(j)];
        float2 a1 = cmulf(w1, src[PHY(j + 256)]);
        float2 a2 = cmulf(w2, src[PHY(j + 512)]);
        float2 a3 = cmulf(w3, src[PHY(j + 768)]);
        float2 t0 = make_float2(a0.x + a2.x, a0.y + a2.y);
        float2 t1 = make_float2(a0.x - a2.x, a0.y - a2.y);
        float2 t2 = make_float2(a1.x + a3.x, a1.y + a3.y);
        float2 t3 = make_float2(a1.x - a3.x, a1.y - a3.y);
        float2 u3 = INV ? make_float2(-t3.y, t3.x) : make_float2(t3.y, -t3.x);
        const int base = ((j >> (2 * t)) << (2 * t + 2)) + k;
        dst[PHY(base)]          = make_float2(t0.x + t2.x, t0.y + t2.y);
        dst[PHY(base + Ns)]     = make_float2(t1.x + u3.x, t1.y + u3.y);
        dst[PHY(base + 2 * Ns)] = make_float2(t0.x - t2.x, t0.y - t2.y);
        dst[PHY(base + 3 * Ns)] = make_float2(t1.x - u3.x, t1.y - u3.y);
        float2* tmp = src; src = dst; dst = tmp;
    }
    __syncthreads();
}

// ---------------- kernel 3: per (b, e-chunk): two-for-one FFT + cross-power partials.
// Stage 0 of each FFT runs in registers straight off the coalesced global loads.
__global__ __launch_bounds__(256) void xcorr_kernel(
    float* __restrict__ St, const float* __restrict__ kp_t) {
    __shared__ float2 bufA[1088];
    __shared__ float2 bufB[1088];
    const int tid = threadIdx.x;
    const int b = blockIdx.x / CHUNKS;
    const int chunk = blockIdx.x % CHUNKS;

    float2 p0 = make_float2(0.f, 0.f);
    float2 p1 = make_float2(0.f, 0.f);
    float px2 = 0.f;                      // f=512 (lane 0 only)

    const size_t base = ((size_t)b * EE + (size_t)chunk * EPB) * LL;
    for (int ee = 0; ee < EPB; ++ee) {
        const size_t rbase = base + (size_t)ee * LL;
        __syncthreads();   // prior pacc reads of bufA done
        // ---- stage 0 in registers: loads ARE the stage-0 operands
        {
            float2 z0 = make_float2(St[rbase + tid],        kp_t[rbase + tid]);
            float2 z1 = make_float2(St[rbase + tid + 256],  kp_t[rbase + tid + 256]);
            float2 z2 = make_float2(St[rbase + tid + 512],  kp_t[rbase + tid + 512]);
            float2 z3 = make_float2(St[rbase + tid + 768],  kp_t[rbase + tid + 768]);
            float2 t0 = make_float2(z0.x + z2.x, z0.y + z2.y);
            float2 t1 = make_float2(z0.x - z2.x, z0.y - z2.y);
            float2 t2 = make_float2(z1.x + z3.x, z1.y + z3.y);
            float2 t3 = make_float2(z1.x - z3.x, z1.y - z3.y);
            float2 u3 = make_float2(t3.y, -t3.x);            // forward
            const int q = 4 * tid;
            bufA[PHY(q)]     = make_float2(t0.x + t2.x, t0.y + t2.y);
            bufA[PHY(q + 1)] = make_float2(t1.x + u3.x, t1.y + u3.y);
            bufA[PHY(q + 2)] = make_float2(t0.x - t2.x, t0.y - t2.y);
            bufA[PHY(q + 3)] = make_float2(t1.x - u3.x, t1.y - u3.y);
        }
        fft1024_r4_tail<false>(bufA, bufB, tid);   // stages 1..4, result in bufA
        {
            float2 A = bufA[PHY(tid)];
            float2 C = bufA[PHY((1024 - tid) & 1023)];
            p0.x += 0.5f * (A.x * C.y + A.y * C.x);
            p0.y += 0.25f * ((A.x * A.x + A.y * A.y) - (C.x * C.x + C.y * C.y));
        }
        {
            int f = tid + 256;
            float2 A = bufA[PHY(f)];
            float2 C = bufA[PHY(1024 - f)];
            p1.x += 0.5f * (A.x * C.y + A.y * C.x);
            p1.y += 0.25f * ((A.x * A.x + A.y * A.y) - (C.x * C.x + C.y * C.y));
        }
        if (tid == 0) {
            float2 A = bufA[PHY(512)];
            px2 += A.x * A.y;
        }
    }
    float2* pp = (float2*)&St[base];      // own slab head (fully consumed above)
    pp[tid] = p0;
    pp[tid + 256] = p1;
    if (tid == 0) pp[512] = make_float2(px2, 0.f);
}

// ---------------- kernel 4: per b: reduce partials, Hermitian irfft -> mean_value
__global__ __launch_bounds__(256) void ifft_kernel(
    const float* __restrict__ St, float* __restrict__ mv) {
    __shared__ float2 bufA[1088];
    __shared__ float2 bufB[1088];
    const int tid = threadIdx.x;
    const int b = blockIdx.x;
#pragma unroll
    for (int u = 0; u < 2; ++u) {
        int f = tid + (u << 8);            // 0..511
        float2 s = make_float2(0.f, 0.f);
        for (int c = 0; c < CHUNKS; ++c) {
            const float2* pp = (const float2*)&St[((size_t)b * EE + (size_t)c * EPB) * LL];
            float2 v = pp[f];
            s.x += v.x; s.y += v.y;
        }
        if (f == 0) s.y = 0.f;
        bufA[PHY(f)] = s;
        if (f > 0) bufA[PHY(1024 - f)] = make_float2(s.x, -s.y);
    }
    if (tid == 0) {
        float sx = 0.f;
        for (int c = 0; c < CHUNKS; ++c) {
            const float2* pp = (const float2*)&St[((size_t)b * EE + (size_t)c * EPB) * LL];
            sx += pp[512].x;
        }
        bufA[PHY(512)] = make_float2(sx, 0.f);
    }
    fft1024_r4<true>(bufA, bufB, tid);
    const float sc = 1.f / (1024.f * 256.f);
#pragma unroll
    for (int u = 0; u < 4; ++u) {
        int t = tid + (u << 8);
        mv[(size_t)b * LL + t] = bufB[PHY(t)].x * sc;
    }
}

// ---------------- kernel 5: batch-mean over b, argmax/argmin over tau
__global__ __launch_bounds__(1024) void argidx_kernel(
    const float* __restrict__ mv, int* __restrict__ istats) {
    __shared__ float smax[1024], smin[1024];
    __shared__ int imax[1024], imin[1024];
    const int t = threadIdx.x;
    float g = 0.f;
    for (int b = 0; b < BB; ++b) g += mv[(size_t)b * LL + t];
    smax[t] = g; smin[t] = g; imax[t] = t; imin[t] = t;
    __syncthreads();
    for (int s = 512; s > 0; s >>= 1) {
        if (t < s) {
            if (smax[t + s] > smax[t] ||
                (smax[t + s] == smax[t] && imax[t + s] < imax[t])) {
                smax[t] = smax[t + s]; imax[t] = imax[t + s];
            }
            if (smin[t + s] < smin[t] ||
                (smin[t + s] == smin[t] && imin[t + s] > imin[t])) {
                smin[t] = smin[t + s]; imin[t] = imin[t + s];
            }
        }
        __syncthreads();
    }
    if (t == 0) { istats[0] = imax[0]; istats[1] = imin[0]; }
}

// ---------------- kernel 6: per-b softmax weights at idx0 / idx1
__global__ __launch_bounds__(256) void softmax_kernel(
    const float* __restrict__ mv, const int* __restrict__ istats,
    float* __restrict__ w01) {
    __shared__ float red[256];
    const int b = blockIdx.x, t = threadIdx.x;
    const float scale = 0.0625f;
    const float* row = mv + (size_t)b * LL;
    float m = -INFINITY;
    for (int i = t; i < LL; i += 256) m = fmaxf(m, row[i]);
    red[t] = m; __syncthreads();
    for (int s = 128; s > 0; s >>= 1) {
        if (t < s) red[t] = fmaxf(red[t], red[t + s]);
        __syncthreads();
    }
    m = red[0]; __syncthreads();
    float sum = 0.f;
    for (int i = t; i < LL; i += 256) sum += expf((row[i] - m) * scale);
    red[t] = sum; __syncthreads();
    for (int s = 128; s > 0; s >>= 1) {
        if (t < s) red[t] += red[t + s];
        __syncthreads();
    }
    if (t == 0) {
        float denom = red[0];
        w01[b]      = expf((row[istats[0]] - m) * scale) / denom;
        w01[BB + b] = expf((row[istats[1]] - m) * scale) / denom;
    }
}

// ---------------- kernel 7: gather rolled vsub columns, scale, write out
__global__ __launch_bounds__(256) void out_kernel(
    const float* __restrict__ vsub, const int* __restrict__ istats,
    const float* __restrict__ w01, float* __restrict__ out) {
    const int i = blockIdx.x * 256 + threadIdx.x;
    const int half = (i >= BB * LL * KK) ? 1 : 0;
    const int j = i - half * BB * LL * KK;
    const int b = j / (LL * KK);
    const int rem = j % (LL * KK);
    const int l = rem / KK, kk = rem % KK;
    const int sh = istats[half];
    const int lr = (l + sh) & (LL - 1);
    const float w = w01[half * BB + b];
    out[i] = vsub[(size_t)(b * LL + lr) * 16 + half * 8 + kk] * w;
}

extern "C" void kernel_launch(void* const* d_in, const int* in_sizes, int n_in,
                              void* d_out, int out_size, void* d_ws, size_t ws_size,
                              hipStream_t stream) {
    const float* S  = (const float*)d_in[0];
    const float* T  = (const float*)d_in[1];
    const float* Wq = (const float*)d_in[2];
    const float* Wk = (const float*)d_in[4];
    const float* Wv = (const float*)d_in[6];
    const float* bv = (const float*)d_in[7];

    float* ws    = (float*)d_ws;
    unsigned short* mhiT = (unsigned short*)(ws + O_MHI);
    unsigned short* mloT = (unsigned short*)(ws + O_MLO);
    float* bvaug = ws + O_BVAUG;
    unsigned short* thiT = (unsigned short*)(ws + O_X);
    unsigned short* tloT = (unsigned short*)(ws + O_X + 8388608);
    float* st    = ws + O_X;                  // aliases ThiT/TloT (after gemm)
    float* kp_t  = ws + O_KPT;
    float* vsub  = ws + O_VSUB;
    float* mv    = ws + O_MV;
    float* stats = ws + O_STATS;
    int*   istats = (int*)stats;
    float* w01    = stats + 8;

    build_maug<<<272, 256, 0, stream>>>(Wq, Wk, Wv, bv, mhiT, mloT, bvaug);
    split_T<<<(BB * LL * EE) / (256 * 8), 256, 0, stream>>>(T, thiT, tloT);
    gemm_mfma<<<(BB * LL) / 64, 256, 0, stream>>>(thiT, tloT, mhiT, mloT, bvaug, kp_t, vsub);
    dim3 gT(LL / 64, EE / 64, BB);
    transpose_S<<<gT, 256, 0, stream>>>(S, st);   // overwrites ThiT/TloT (consumed by gemm)
    xcorr_kernel<<<BB * CHUNKS, 256, 0, stream>>>(st, kp_t);
    ifft_kernel<<<BB, 256, 0, stream>>>(st, mv);
    argidx_kernel<<<1, 1024, 0, stream>>>(mv, istats);
    softmax_kernel<<<BB, 256, 0, stream>>>(mv, istats, w01);
    out_kernel<<<(2 * BB * LL * KK) / 256, 256, 0, stream>>>(vsub, istats, w01, (float*)d_out);
}